// Round 8
// baseline (64.669 us; speedup 1.0000x reference)
//
#include <hip/hip_runtime.h>
#include <hip/hip_bf16.h>
#include <math.h>

#define BB  4
#define TT  8192
#define DD  64
#define PP  8
#define CC  64            // chunk length along t
#define NCH (TT/CC)       // 128 chunks
#define SSTR 65           // pass2 WvT SH stride

#define EPSV 1e-3f
#define KPI4 0.78539816339744830962f

typedef __attribute__((ext_vector_type(8))) short short8;   // 8 bf16
typedef __attribute__((ext_vector_type(4))) float f32x4;

__device__ __forceinline__ float bf2f(unsigned short h) {
  return __uint_as_float(((unsigned)h) << 16);
}
__device__ __forceinline__ unsigned short f2bf(float f) {   // RNE
  unsigned u = __float_as_uint(f);
  u += 0x7fffu + ((u >> 16) & 1u);
  return (unsigned short)(u >> 16);
}
__device__ __forceinline__ float fast_tanh(float x) {
  float e = __expf(2.f * x);
  return 1.f - 2.f * __builtin_amdgcn_rcpf(e + 1.f);
}
__device__ __forceinline__ float rlane(float v, int lane) {
  return __uint_as_float(__builtin_amdgcn_readlane(__float_as_uint(v), lane));
}

// ---- Pass 1: dots+trig+scan per (t,p); d-space aggregates + quarter partials ----
__global__ __launch_bounds__(512) void k_pass1(const float* __restrict__ q,
                                               const float* __restrict__ Wq,
                                               const float* __restrict__ Wk,
                                               float* __restrict__ aggC,
                                               float* __restrict__ aggM,
                                               float* __restrict__ aggS,
                                               float4* __restrict__ T4,
                                               float2* __restrict__ T2) {
  const int blk = blockIdx.x;               // b*NCH + c
  const int c = blk & (NCH - 1);
  const int b = blk >> 7;
  const int tid = threadIdx.x;
  const int p = tid >> 6, l = tid & 63;     // wave = p, lane = t (then i)

  const float* qb = q + ((size_t)b * TT + (size_t)c * CC) * DD;

  float ckR, skR;
  {
    const float4* qr  = (const float4*)(qb + l * DD);
    const float4* wqr = (const float4*)(Wq + p * DD);
    const float4* wkr = (const float4*)(Wk + p * DD);
    float dq = 0.f, dk = 0.f;
#pragma unroll
    for (int j = 0; j < 16; ++j) {
      float4 qv = qr[j], w0 = wqr[j], w1 = wkr[j];
      dq = fmaf(qv.x, w0.x, dq); dq = fmaf(qv.y, w0.y, dq);
      dq = fmaf(qv.z, w0.z, dq); dq = fmaf(qv.w, w0.w, dq);
      dk = fmaf(qv.x, w1.x, dk); dk = fmaf(qv.y, w1.y, dk);
      dk = fmaf(qv.z, w1.z, dk); dk = fmaf(qv.w, w1.w, dk);
    }
    float ang = fast_tanh(dq) * KPI4;
    float cq = __cosf(ang), sq = __sinf(ang);
    ang = fast_tanh(dk) * KPI4;
    ckR = __cosf(ang); skR = __sinf(ang);

    // width-64 inclusive scan of ck/sk over t
    float rc = ckR, rs = skR;
#pragma unroll
    for (int d = 1; d < 64; d <<= 1) {
      float tc = __shfl_up(rc, (unsigned)d, 64);
      float ts = __shfl_up(rs, (unsigned)d, 64);
      if (l >= d) { rc += tc; rs += ts; }
    }
    const size_t idx = ((size_t)(b * NCH + c) * PP + p) * 64 + l;
    T4[idx] = make_float4(cq, sq, ckR, skR);
    T2[idx] = make_float2(rc, rs);
    if (l == 63)
      *(float2*)(aggS + ((size_t)(b * PP + p) * NCH + c) * 2) = make_float2(rc, rs);
  }

  // d-space aggregates + quarter partials: wave p, lane i = l.
  {
    const int i = l;
    float c0 = 0.f, s0 = 0.f;
    float* am = aggM + ((size_t)(b * PP + p) * NCH + c) * 384;
#pragma unroll
    for (int t = 0; t < CC; ++t) {
      if (t == 16 || t == 32 || t == 48) {
        float* d0 = am + (t / 16 - 1) * 128;
        d0[i] = c0; d0[64 + i] = s0;
      }
      float qv = qb[t * DD + i];             // coalesced row read
      c0 = fmaf(rlane(ckR, t), qv, c0);
      s0 = fmaf(rlane(skR, t), qv, s0);
    }
    float* a0 = aggC + ((size_t)(b * PP + p) * NCH + c) * 128;
    a0[i] = c0; a0[64 + i] = s0;
  }
}

// ---- Pass 2: exclusive scan over 128 chunks; blocks 0..7 build WvT hi/lo ----
__global__ __launch_bounds__(576) void k_pass2(float* __restrict__ aggC,
                                               float* __restrict__ aggS,
                                               const float* __restrict__ Wv,
                                               unsigned short* __restrict__ WvTh,
                                               unsigned short* __restrict__ WvTl) {
  const int bp = blockIdx.x;
  const int tid = threadIdx.x;
  __shared__ float totals[4][132];
  __shared__ float SH[64 * SSTR];

  const bool act = tid < 520;
  int seg = 0, m = 0;
  float* base = aggC;
  int stride = 128;
  float vals[32];
  if (act) {
    seg = tid / 130;
    m = tid - seg * 130;
    if (m < 128) { base = aggC + (size_t)bp * NCH * 128 + m; stride = 128; }
    else         { base = aggS + (size_t)bp * NCH * 2 + (m - 128); stride = 2; }
    float run = 0.f;
#pragma unroll
    for (int u = 0; u < 32; ++u) vals[u] = base[(size_t)(seg * 32 + u) * stride];
#pragma unroll
    for (int u = 0; u < 32; ++u) run += vals[u];
    totals[seg][m] = run;
  }
  __syncthreads();
  if (act) {
    float r2 = 0.f;
    for (int s = 0; s < seg; ++s) r2 += totals[s][m];
#pragma unroll
    for (int u = 0; u < 32; ++u) {
      float v = vals[u];
      base[(size_t)(seg * 32 + u) * stride] = r2;
      r2 += v;
    }
  }

  if (bp < 8) {
    const int k0 = bp * 64;
    __syncthreads();
    for (int idx = tid; idx < 4096; idx += 576) {
      int kk = idx >> 6, o = idx & 63;
      SH[o * SSTR + kk] = Wv[(size_t)(k0 + kk) * DD + o];
    }
    __syncthreads();
    for (int idx = tid; idx < 4096; idx += 576) {
      int o = idx >> 6, kk = idx & 63;
      float wv = SH[o * SSTR + kk];
      unsigned short hi = f2bf(wv);
      WvTh[(size_t)o * 512 + k0 + kk] = hi;
      WvTl[(size_t)o * 512 + k0 + kk] = f2bf(wv - bf2f(hi));
    }
  }
}

// ---- Pass 3: CC=64 blocks: scan->Z(hi/lo, swizzled, b32-packed) -> MFMA ----
__global__ __launch_bounds__(512, 4) void k_pass3(
    const float* __restrict__ q, const float* __restrict__ Wo,
    const float* __restrict__ aggC, const float* __restrict__ aggM,
    const float* __restrict__ aggS,
    const float4* __restrict__ T4, const float2* __restrict__ T2,
    const unsigned short* __restrict__ WvTh,
    const unsigned short* __restrict__ WvTl,
    float* __restrict__ out) {
  const int blk = blockIdx.x;               // b*NCH + c
  const int c = blk & (NCH - 1);
  const int b = blk >> 7;

  __shared__ __align__(16) short Zbuf[2 * CC * 256];   // 64 KB: Zh | Zl (rows 512 B)
  __shared__ float4 trig4[PP][CC];                     // 8 KB {ck,sk,al,be}

  const int tid = threadIdx.x;
  const int w = tid >> 6, l = tid & 63;
  const int lm = l & 15, lg = l >> 4;
  const int oc = (w & 3) << 4;              // o-cols
  const int tr = (w >> 2) << 5;             // t-tile base {0,32}

  // Prefetch khalf0 B-fragments into registers.
  short8 bhf[8], blf[8];
  {
    const unsigned short* ph_ = WvTh + (size_t)(oc + lm) * 512 + lg * 8;
    const unsigned short* pl_ = WvTl + (size_t)(oc + lm) * 512 + lg * 8;
#pragma unroll
    for (int kk = 0; kk < 8; ++kk) {
      bhf[kk] = *(const short8*)(ph_ + kk * 32);
      blf[kk] = *(const short8*)(pl_ + kk * 32);
    }
  }

  const float* qb = q + ((size_t)b * TT + (size_t)c * CC) * DD;

  // Phase A: (t=l, p=w) — finish denom, stage {ck,sk,al,be}.
  {
    const size_t idx = ((size_t)(b * NCH + c) * PP + w) * 64 + l;
    float4 t4 = T4[idx];
    float2 t2 = T2[idx];
    float2 RC = *(const float2*)(aggS + ((size_t)(b * PP + w) * NCH + c) * 2);
    float rc = t2.x + RC.x, rs = t2.y + RC.y;
    float den = fmaf(t4.x, rc, fmaf(t4.y, rs, EPSV));
    float ws = Wo[w] * __builtin_amdgcn_rcpf(den);
    trig4[w][l] = make_float4(t4.z, t4.w, ws * t4.x, ws * t4.y);
  }
  __syncthreads();                         // barrier 1: trig4 is read cross-wave

  const int j = l & 31;                    // i-pair index: i = 2j, 2j+1
  const int qt = ((w >> 2) << 1) | (l >> 5);  // t-quarter 0..3
  const int t0 = qt << 4;
  const int i0 = j << 1;
  char* zbase = (char*)Zbuf;
  f32x4 acc0 = {0, 0, 0, 0}, acc1 = {0, 0, 0, 0};

  auto phaseB = [&](int p) {
    const float* prC = aggC + ((size_t)(b * PP + p) * NCH + c) * 128;
    float AcX = prC[i0], AcY = prC[i0 + 1];
    float AsX = prC[64 + i0], AsY = prC[64 + i0 + 1];
    if (qt) {
      const float* pm = aggM + (((size_t)(b * PP + p) * NCH + c) * 3 + (qt - 1)) * 128;
      AcX += pm[i0]; AcY += pm[i0 + 1];
      AsX += pm[64 + i0]; AsY += pm[64 + i0 + 1];
    }
    const int kb = ((p & 3) << 7) + (j << 2);   // byte offset in 512-B Z row
#pragma unroll
    for (int tt = 0; tt < 16; ++tt) {
      const int t = t0 + tt;
      float2 qv = *(const float2*)(qb + t * DD + i0);
      float4 v = trig4[p][t];
      AcX = fmaf(v.x, qv.x, AcX); AsX = fmaf(v.y, qv.x, AsX);
      AcY = fmaf(v.x, qv.y, AcY); AsY = fmaf(v.y, qv.y, AsY);
      float zx = fmaf(v.z, AcX, v.w * AsX);
      float zy = fmaf(v.z, AcY, v.w * AsY);
      unsigned ux = __float_as_uint(zx);
      unsigned rx = ux + 0x7fffu + ((ux >> 16) & 1u);
      unsigned uy = __float_as_uint(zy);
      unsigned ry = uy + 0x7fffu + ((uy >> 16) & 1u);
      unsigned hpack = (rx >> 16) | (ry & 0xffff0000u);
      float lx = zx - __uint_as_float(rx & 0xffff0000u);
      float ly = zy - __uint_as_float(ry & 0xffff0000u);
      unsigned lpack = (__float_as_uint(lx) >> 16) | (__float_as_uint(ly) & 0xffff0000u);
      const int ad = (t << 9) + (kb ^ ((t & 7) << 4));
      *(unsigned*)(zbase + ad) = hpack;
      *(unsigned*)(zbase + 32768 + ad) = lpack;
    }
  };

  auto phaseC = [&]() {
#pragma unroll
    for (int kk = 0; kk < 8; ++kk) {
      const int sw = (kk * 64 + lg * 16) ^ ((lm & 7) << 4);
      const int rb0 = ((tr + lm) << 9) + sw;
      const int rb1 = ((tr + 16 + lm) << 9) + sw;
      short8 ah0 = *(const short8*)(zbase + rb0);
      short8 al0 = *(const short8*)(zbase + 32768 + rb0);
      short8 ah1 = *(const short8*)(zbase + rb1);
      short8 al1 = *(const short8*)(zbase + 32768 + rb1);
      acc0 = __builtin_amdgcn_mfma_f32_16x16x32_bf16(ah0, bhf[kk], acc0, 0, 0, 0);
      acc1 = __builtin_amdgcn_mfma_f32_16x16x32_bf16(ah1, bhf[kk], acc1, 0, 0, 0);
      acc0 = __builtin_amdgcn_mfma_f32_16x16x32_bf16(al0, bhf[kk], acc0, 0, 0, 0);
      acc1 = __builtin_amdgcn_mfma_f32_16x16x32_bf16(al1, bhf[kk], acc1, 0, 0, 0);
      acc0 = __builtin_amdgcn_mfma_f32_16x16x32_bf16(ah0, blf[kk], acc0, 0, 0, 0);
      acc1 = __builtin_amdgcn_mfma_f32_16x16x32_bf16(ah1, blf[kk], acc1, 0, 0, 0);
    }
  };

  phaseB(w & 3);            // K-half 0: p = 0..3
  __syncthreads();          // barrier 2: Z ready
  phaseC();
  {                         // prefetch khalf1 B-fragments (hides under B1)
    const unsigned short* ph_ = WvTh + (size_t)(oc + lm) * 512 + 256 + lg * 8;
    const unsigned short* pl_ = WvTl + (size_t)(oc + lm) * 512 + 256 + lg * 8;
#pragma unroll
    for (int kk = 0; kk < 8; ++kk) {
      bhf[kk] = *(const short8*)(ph_ + kk * 32);
      blf[kk] = *(const short8*)(pl_ + kk * 32);
    }
  }
  __syncthreads();          // barrier 3: Z consumed, safe to rewrite
  phaseB(4 + (w & 3));      // K-half 1: p = 4..7
  __syncthreads();          // barrier 4: Z ready
  phaseC();

  // Epilogue: C/D layout col=lane&15 (o), row=(lane>>4)*4+reg (t)  [m89]
  {
    float* ob = out + ((size_t)b * TT + (size_t)c * CC + tr + lg * 4) * DD + oc + lm;
#pragma unroll
    for (int r = 0; r < 4; ++r) {
      ob[r * DD] = acc0[r];
      ob[(16 + r) * DD] = acc1[r];
    }
  }
}

extern "C" void kernel_launch(void* const* d_in, const int* in_sizes, int n_in,
                              void* d_out, int out_size, void* d_ws, size_t ws_size,
                              hipStream_t stream) {
  const float* q  = (const float*)d_in[0];
  const float* Wq = (const float*)d_in[1];
  const float* Wk = (const float*)d_in[2];
  const float* Wv = (const float*)d_in[3];
  const float* Wo = (const float*)d_in[4];
  float* out = (float*)d_out;

  float* aggC = (float*)d_ws;                               // 2 MiB
  float* aggM = aggC + (size_t)BB * PP * NCH * 128;         // 6 MiB
  float* aggS = aggM + (size_t)BB * PP * NCH * 384;         // 32 KiB
  unsigned short* WvTh = (unsigned short*)(aggS + (size_t)BB * PP * NCH * 2);
  unsigned short* WvTl = WvTh + (size_t)512 * 64;           // 64 KiB each
  float4* T4 = (float4*)(WvTl + (size_t)512 * 64);          // 4 MiB
  float2* T2 = (float2*)(T4 + (size_t)BB * NCH * PP * 64);  // 2 MiB

  k_pass1<<<BB * NCH, 512, 0, stream>>>(q, Wq, Wk, aggC, aggM, aggS, T4, T2);
  k_pass2<<<BB * PP, 576, 0, stream>>>(aggC, aggS, Wv, WvTh, WvTl);
  k_pass3<<<BB * NCH, 512, 0, stream>>>(q, Wo, aggC, aggM, aggS, T4, T2, WvTh, WvTl, out);
}

// Round 11
// 47.325 us; speedup vs baseline: 1.3665x; 1.3665x over previous
//
#include <hip/hip_runtime.h>
#include <hip/hip_bf16.h>
#include <math.h>

#define BB  4
#define TT  8192
#define DD  64
#define PP  8
#define CC  32            // chunk length along t
#define NCH (TT/CC)       // 256 chunks
#define AGG_STRIDE 130    // 64 cos-d + 64 sin-d + cosK + sinK
#define QSTR 68           // padded Q row stride (floats)
#define TSTR 33           // padded per-p trig stride

#define EPSV 1e-3f
#define KPI4 0.78539816339744830962f

typedef __attribute__((ext_vector_type(8))) short short8;   // 8 bf16
typedef __attribute__((ext_vector_type(4))) float f32x4;

__device__ __forceinline__ float bf2f(unsigned short h) {
  return __uint_as_float(((unsigned)h) << 16);
}
__device__ __forceinline__ unsigned short f2bf(float f) {   // RNE
  unsigned u = __float_as_uint(f);
  u += 0x7fffu + ((u >> 16) & 1u);
  return (unsigned short)(u >> 16);
}
__device__ __forceinline__ float fast_tanh(float x) {
  float e = __expf(2.f * x);
  return 1.f - 2.f * __builtin_amdgcn_rcpf(e + 1.f);
}
// Z swizzle: row stride 512B, XOR byte-bits 4..6 by row&7 (quad-uniform b128 reads)
__device__ __forceinline__ int zswz(int row, int kb) {
  return (row << 9) + (kb ^ ((row & 7) << 4));
}

// ---- Pass 1: per-(b,chunk) aggregates; blocks 0..63 also build WvT hi/lo ----
__global__ __launch_bounds__(256) void k_pass1(const float* __restrict__ q,
                                               const float* __restrict__ Wk,
                                               const float* __restrict__ Wv,
                                               float* __restrict__ agg,
                                               unsigned short* __restrict__ WvTh,
                                               unsigned short* __restrict__ WvTl) {
  const int blk = blockIdx.x;
  const int c = blk & (NCH - 1);
  const int b = blk >> 8;

  __shared__ float SH[64 * QSTR];           // Qs (32 rows); reused for Wv transpose
  __shared__ float Wks[PP * DD];
  __shared__ float cks[PP * TSTR], sks[PP * TSTR];

  const int tid = threadIdx.x;
  const float* qb = q + ((size_t)b * TT + (size_t)c * CC) * DD;
  for (int g = tid; g < CC * DD; g += 256) SH[(g >> 6) * QSTR + (g & 63)] = qb[g];
  for (int g = tid; g < PP * DD; g += 256) Wks[g] = Wk[g];
  __syncthreads();

  {  // k-dots + trig: thread = (t, p)
    const int t = tid & 31, p = tid >> 5;
    float dk = 0.f;
    const float4* qr = (const float4*)&SH[t * QSTR];
    const float4* wr = (const float4*)&Wks[p * DD];
#pragma unroll
    for (int j = 0; j < 16; ++j) {
      float4 qv = qr[j], wv = wr[j];
      dk = fmaf(qv.x, wv.x, dk); dk = fmaf(qv.y, wv.y, dk);
      dk = fmaf(qv.z, wv.z, dk); dk = fmaf(qv.w, wv.w, dk);
    }
    float ang = fast_tanh(dk) * KPI4;
    cks[p * TSTR + t] = __cosf(ang);
    sks[p * TSTR + t] = __sinf(ang);
  }
  __syncthreads();

  {  // d-space aggregates: thread = (i, p-pair)
    const int i = tid & 63, pq = tid >> 6;
    const int p0 = pq, p1 = pq + 4;
    float c0 = 0, s0 = 0, c1 = 0, s1 = 0;
#pragma unroll
    for (int t = 0; t < CC; ++t) {
      float qv = SH[t * QSTR + i];
      c0 = fmaf(cks[p0 * TSTR + t], qv, c0);
      s0 = fmaf(sks[p0 * TSTR + t], qv, s0);
      c1 = fmaf(cks[p1 * TSTR + t], qv, c1);
      s1 = fmaf(sks[p1 * TSTR + t], qv, s1);
    }
    float* a0 = agg + (size_t)((b * PP + p0) * NCH + c) * AGG_STRIDE;
    float* a1 = agg + (size_t)((b * PP + p1) * NCH + c) * AGG_STRIDE;
    a0[i] = c0; a0[64 + i] = s0;
    a1[i] = c1; a1[64 + i] = s1;
  }
  if (tid < 16) {  // scalar cos/sin sums
    const int p = tid & 7;
    float s2 = 0.f;
    if (tid < 8) {
      for (int t = 0; t < CC; ++t) s2 += cks[p * TSTR + t];
      agg[(size_t)((b * PP + p) * NCH + c) * AGG_STRIDE + 128] = s2;
    } else {
      for (int t = 0; t < CC; ++t) s2 += sks[p * TSTR + t];
      agg[(size_t)((b * PP + p) * NCH + c) * AGG_STRIDE + 129] = s2;
    }
  }

  // Wv transpose + double-bf16 split: blocks 0..63, one 8-k tile each.
  if (blk < 64) {
    __syncthreads();
    const int k0 = blk * 8;
#pragma unroll
    for (int r = 0; r < 2; ++r) {
      int idx = tid + r * 256;
      int kk = idx >> 6, o = idx & 63;                   // coalesced over o
      SH[o * QSTR + kk] = Wv[(size_t)(k0 + kk) * DD + o];
    }
    __syncthreads();
#pragma unroll
    for (int r = 0; r < 2; ++r) {
      int idx = tid + r * 256;
      int o = idx >> 3, kk = idx & 7;                    // coalesced over kk
      float wv = SH[o * QSTR + kk];
      unsigned short hi = f2bf(wv);
      WvTh[(size_t)o * 512 + k0 + kk] = hi;
      WvTl[(size_t)o * 512 + k0 + kk] = f2bf(wv - bf2f(hi));
    }
  }
}

// ---- Pass 2: hierarchical exclusive scan over 256 chunks, 4-way segmented ----
__global__ __launch_bounds__(576) void k_pass2(float* __restrict__ agg) {
  const int bp = blockIdx.x;
  const int tid = threadIdx.x;
  __shared__ float totals[4][132];

  const bool act = tid < 520;
  int seg = 0, m = 0;
  float* base = agg;
  float vals[64];
  if (act) {
    seg = tid / 130;
    m = tid - seg * 130;
    base = agg + (size_t)bp * NCH * AGG_STRIDE + m;
    float run = 0.f;
#pragma unroll
    for (int u = 0; u < 64; ++u) vals[u] = base[(size_t)(seg * 64 + u) * AGG_STRIDE];
#pragma unroll
    for (int u = 0; u < 64; ++u) run += vals[u];
    totals[seg][m] = run;
  }
  __syncthreads();
  if (act) {
    float r2 = 0.f;
    for (int s = 0; s < seg; ++s) r2 += totals[s][m];
#pragma unroll
    for (int u = 0; u < 64; ++u) {
      float v = vals[u];
      base[(size_t)(seg * 64 + u) * AGG_STRIDE] = r2;
      r2 += v;
    }
  }
}

// ---- Pass 3: trig+scan -> Z(hi/lo bf16, swizzled) -> 3-term MFMA GEMM ----
__global__ __launch_bounds__(256, 3) void k_pass3(
    const float* __restrict__ q, const float* __restrict__ Wq,
    const float* __restrict__ Wk, const float* __restrict__ Wo,
    const float* __restrict__ pref,
    const unsigned short* __restrict__ WvTh,
    const unsigned short* __restrict__ WvTl,
    float* __restrict__ out) {
  const int blk = blockIdx.x;
  const int c = blk & (NCH - 1);
  const int b = blk >> 8;

  __shared__ float Qs[CC * QSTR];                          // 8.7 KB
  __shared__ float Wqs[PP * DD], Wks[PP * DD];             // 4 KB
  __shared__ float cqs[PP * TSTR], sqs[PP * TSTR];         // 2.1 KB
  __shared__ float cks[PP * TSTR], sks[PP * TSTR];         // 2.1 KB
  __shared__ float scs[PP * TSTR];                         // 1.06 KB
  __shared__ __align__(16) short Zh[CC * 256];             // 16 KB (swizzled)
  __shared__ __align__(16) short Zl[CC * 256];             // 16 KB

  const int tid = threadIdx.x;
  const int w = tid >> 6, l = tid & 63;
  const int lm = l & 15, lg = l >> 4;
  const int oc = w << 4;                                   // wave's 16 o-cols

  // Prefetch h=0 B-fragments (WvT) into registers — independent of all LDS.
  short8 bhf[8], blf[8];
  {
    const unsigned short* ph_ = WvTh + (size_t)(oc + lm) * 512 + lg * 8;
    const unsigned short* pl_ = WvTl + (size_t)(oc + lm) * 512 + lg * 8;
#pragma unroll
    for (int kk = 0; kk < 8; ++kk) {
      bhf[kk] = *(const short8*)(ph_ + kk * 32);
      blf[kk] = *(const short8*)(pl_ + kk * 32);
    }
  }

  const float* qb = q + ((size_t)b * TT + (size_t)c * CC) * DD;
  for (int g = tid; g < CC * DD; g += 256) Qs[(g >> 6) * QSTR + (g & 63)] = qb[g];
  for (int g = tid; g < PP * DD; g += 256) { Wqs[g] = Wq[g]; Wks[g] = Wk[g]; }
  __syncthreads();

  // Phase A: dots + trig + in-segment shfl scan -> scs (no serial A2).
  {
    const int t = tid & 31, p = tid >> 5;
    float dq = 0.f, dk = 0.f;
    const float4* qr  = (const float4*)&Qs[t * QSTR];
    const float4* wqr = (const float4*)&Wqs[p * DD];
    const float4* wkr = (const float4*)&Wks[p * DD];
#pragma unroll
    for (int j = 0; j < 16; ++j) {
      float4 qv = qr[j], w0 = wqr[j], w1 = wkr[j];
      dq = fmaf(qv.x, w0.x, dq); dq = fmaf(qv.y, w0.y, dq);
      dq = fmaf(qv.z, w0.z, dq); dq = fmaf(qv.w, w0.w, dq);
      dk = fmaf(qv.x, w1.x, dk); dk = fmaf(qv.y, w1.y, dk);
      dk = fmaf(qv.z, w1.z, dk); dk = fmaf(qv.w, w1.w, dk);
    }
    float ang = fast_tanh(dq) * KPI4;
    float cq = __cosf(ang), sq = __sinf(ang);
    cqs[p * TSTR + t] = cq; sqs[p * TSTR + t] = sq;
    ang = fast_tanh(dk) * KPI4;
    float ck = __cosf(ang), sk = __sinf(ang);
    cks[p * TSTR + t] = ck; sks[p * TSTR + t] = sk;

    // width-32 inclusive scan over t of (ck, sk), per p-segment
    float rc = ck, rs = sk;
#pragma unroll
    for (int d = 1; d < 32; d <<= 1) {
      float tc = __shfl_up(rc, (unsigned)d, 32);
      float ts = __shfl_up(rs, (unsigned)d, 32);
      if (t >= d) { rc += tc; rs += ts; }
    }
    const float* pr = pref + (size_t)((b * PP + p) * NCH + c) * AGG_STRIDE;
    rc += pr[128]; rs += pr[129];
    float den = fmaf(cq, rc, fmaf(sq, rs, EPSV));
    scs[p * TSTR + t] = Wo[p] * __builtin_amdgcn_rcpf(den);
  }
  __syncthreads();

  char* zbaseH = (char*)Zh;
  char* zbaseL = (char*)Zl;
  f32x4 acc0 = {0, 0, 0, 0}, acc1 = {0, 0, 0, 0};

#pragma unroll
  for (int h = 0; h < 2; ++h) {
    {  // Phase B(h): thread = (i=l, ph=w); p = h*4+w; k_half = w*64+l.
      const int p = h * 4 + w;
      const float* prC = pref + (size_t)((b * PP + p) * NCH + c) * AGG_STRIDE;
      float Ac = prC[l], As = prC[64 + l];
      const int kb = (w * 64 + l) * 2;     // byte offset of this k in a Z row
#pragma unroll 8
      for (int t = 0; t < CC; ++t) {
        float qv = Qs[t * QSTR + l];
        Ac = fmaf(cks[p * TSTR + t], qv, Ac);
        As = fmaf(sks[p * TSTR + t], qv, As);
        float z = scs[p * TSTR + t] * fmaf(cqs[p * TSTR + t], Ac, sqs[p * TSTR + t] * As);
        unsigned u = __float_as_uint(z);
        unsigned r = u + 0x7fffu + ((u >> 16) & 1u);
        int zb = zswz(t, kb);
        *(short*)(zbaseH + zb) = (short)(r >> 16);
        float lo = z - __uint_as_float(r & 0xffff0000u);
        *(short*)(zbaseL + zb) = (short)(__float_as_uint(lo) >> 16);
      }
    }
    __syncthreads();
    // Phase C(h): pure ds_read + MFMA (B-frags already in registers).
#pragma unroll
    for (int kk = 0; kk < 8; ++kk) {
      const int rb0 = zswz(lm, kk * 64 + lg * 16);
      const int rb1 = zswz(16 + lm, kk * 64 + lg * 16);
      short8 ah0 = *(const short8*)(zbaseH + rb0);
      short8 al0 = *(const short8*)(zbaseL + rb0);
      short8 ah1 = *(const short8*)(zbaseH + rb1);
      short8 al1 = *(const short8*)(zbaseL + rb1);
      acc0 = __builtin_amdgcn_mfma_f32_16x16x32_bf16(ah0, bhf[kk], acc0, 0, 0, 0);
      acc1 = __builtin_amdgcn_mfma_f32_16x16x32_bf16(ah1, bhf[kk], acc1, 0, 0, 0);
      acc0 = __builtin_amdgcn_mfma_f32_16x16x32_bf16(al0, bhf[kk], acc0, 0, 0, 0);
      acc1 = __builtin_amdgcn_mfma_f32_16x16x32_bf16(al1, bhf[kk], acc1, 0, 0, 0);
      acc0 = __builtin_amdgcn_mfma_f32_16x16x32_bf16(ah0, blf[kk], acc0, 0, 0, 0);
      acc1 = __builtin_amdgcn_mfma_f32_16x16x32_bf16(ah1, blf[kk], acc1, 0, 0, 0);
    }
    if (h == 0) {  // prefetch h=1 B-fragments; latency hides under B(1)
      const unsigned short* ph_ = WvTh + (size_t)(oc + lm) * 512 + 256 + lg * 8;
      const unsigned short* pl_ = WvTl + (size_t)(oc + lm) * 512 + 256 + lg * 8;
#pragma unroll
      for (int kk = 0; kk < 8; ++kk) {
        bhf[kk] = *(const short8*)(ph_ + kk * 32);
        blf[kk] = *(const short8*)(pl_ + kk * 32);
      }
    }
    __syncthreads();
  }

  // Epilogue: C/D layout col=lane&15 (o), row=(lane>>4)*4+reg (t)  [m89]
  {
    float* ob = out + ((size_t)b * TT + (size_t)c * CC + lg * 4) * DD + oc + lm;
#pragma unroll
    for (int r = 0; r < 4; ++r) {
      ob[r * DD] = acc0[r];
      ob[(16 + r) * DD] = acc1[r];
    }
  }
}

extern "C" void kernel_launch(void* const* d_in, const int* in_sizes, int n_in,
                              void* d_out, int out_size, void* d_ws, size_t ws_size,
                              hipStream_t stream) {
  const float* q  = (const float*)d_in[0];
  const float* Wq = (const float*)d_in[1];
  const float* Wk = (const float*)d_in[2];
  const float* Wv = (const float*)d_in[3];
  const float* Wo = (const float*)d_in[4];
  float* out = (float*)d_out;
  float* agg = (float*)d_ws;  // BB*PP*NCH*130 floats = 4,259,840 B
  unsigned short* WvTh = (unsigned short*)(agg + (size_t)BB * PP * NCH * AGG_STRIDE);
  unsigned short* WvTl = WvTh + (size_t)512 * 64;   // +64 KB each

  k_pass1<<<BB * NCH, 256, 0, stream>>>(q, Wk, Wv, agg, WvTh, WvTl);
  k_pass2<<<BB * PP, 576, 0, stream>>>(agg);
  k_pass3<<<BB * NCH, 256, 0, stream>>>(q, Wq, Wk, Wo, agg, WvTh, WvTl, out);
}

// Round 12
// 44.857 us; speedup vs baseline: 1.4417x; 1.0550x over previous
//
#include <hip/hip_runtime.h>
#include <hip/hip_bf16.h>
#include <math.h>

#define BB  4
#define TT  8192
#define DD  64
#define PP  8
#define CC  32            // chunk length along t
#define NCH (TT/CC)       // 256 chunks
#define AGG_STRIDE 130    // 64 cos-d + 64 sin-d + cosK + sinK
#define QSTR 68           // padded Q row stride (floats)

#define EPSV 1e-3f
#define KPI4 0.78539816339744830962f

typedef __attribute__((ext_vector_type(8))) short short8;   // 8 bf16
typedef __attribute__((ext_vector_type(4))) float f32x4;

__device__ __forceinline__ float bf2f(unsigned short h) {
  return __uint_as_float(((unsigned)h) << 16);
}
__device__ __forceinline__ unsigned short f2bf(float f) {   // RNE
  unsigned u = __float_as_uint(f);
  u += 0x7fffu + ((u >> 16) & 1u);
  return (unsigned short)(u >> 16);
}
__device__ __forceinline__ float fast_tanh(float x) {
  float e = __expf(2.f * x);
  return 1.f - 2.f * __builtin_amdgcn_rcpf(e + 1.f);
}

// ---- Pass 1: per-(b,chunk) aggregates; blocks 0..63 also build WvT hi/lo ----
__global__ __launch_bounds__(256) void k_pass1(const float* __restrict__ q,
                                               const float* __restrict__ Wk,
                                               const float* __restrict__ Wv,
                                               float* __restrict__ agg,
                                               unsigned short* __restrict__ WvTh,
                                               unsigned short* __restrict__ WvTl) {
  const int blk = blockIdx.x;
  const int c = blk & (NCH - 1);
  const int b = blk >> 8;

  __shared__ float SH[64 * QSTR];           // Qs (32 rows); reused for Wv transpose
  __shared__ float Wks[PP * DD];
  __shared__ float2 kts[PP * 32];           // {ck, sk}

  const int tid = threadIdx.x;
  const float* qb = q + ((size_t)b * TT + (size_t)c * CC) * DD;
  for (int g = tid; g < CC * DD; g += 256) SH[(g >> 6) * QSTR + (g & 63)] = qb[g];
  for (int g = tid; g < PP * DD; g += 256) Wks[g] = Wk[g];
  __syncthreads();

  {  // k-dots + trig + shfl-reduce sums: thread = (t, p)
    const int t = tid & 31, p = tid >> 5;
    float dk = 0.f;
    const float4* qr = (const float4*)&SH[t * QSTR];
    const float4* wr = (const float4*)&Wks[p * DD];
#pragma unroll
    for (int j = 0; j < 16; ++j) {
      float4 qv = qr[j], wv = wr[j];
      dk = fmaf(qv.x, wv.x, dk); dk = fmaf(qv.y, wv.y, dk);
      dk = fmaf(qv.z, wv.z, dk); dk = fmaf(qv.w, wv.w, dk);
    }
    float ang = fast_tanh(dk) * KPI4;
    float ck = __cosf(ang), sk = __sinf(ang);
    kts[p * 32 + t] = make_float2(ck, sk);
    float rc = ck, rs = sk;
#pragma unroll
    for (int d = 16; d >= 1; d >>= 1) {
      rc += __shfl_xor(rc, d, 32);
      rs += __shfl_xor(rs, d, 32);
    }
    if (t == 0)
      *(float2*)(agg + (size_t)((b * PP + p) * NCH + c) * AGG_STRIDE + 128) =
          make_float2(rc, rs);
  }
  __syncthreads();

  {  // d-space aggregates: thread = (i, p-pair)
    const int i = tid & 63, pq = tid >> 6;
    const int p0 = pq, p1 = pq + 4;
    float c0 = 0, s0 = 0, c1 = 0, s1 = 0;
#pragma unroll
    for (int t = 0; t < CC; ++t) {
      float qv = SH[t * QSTR + i];
      float2 k0v = kts[p0 * 32 + t];
      float2 k1v = kts[p1 * 32 + t];
      c0 = fmaf(k0v.x, qv, c0);
      s0 = fmaf(k0v.y, qv, s0);
      c1 = fmaf(k1v.x, qv, c1);
      s1 = fmaf(k1v.y, qv, s1);
    }
    float* a0 = agg + (size_t)((b * PP + p0) * NCH + c) * AGG_STRIDE;
    float* a1 = agg + (size_t)((b * PP + p1) * NCH + c) * AGG_STRIDE;
    a0[i] = c0; a0[64 + i] = s0;
    a1[i] = c1; a1[64 + i] = s1;
  }

  // Wv transpose + double-bf16 split: blocks 0..63, one 8-k tile each.
  if (blk < 64) {
    __syncthreads();
    const int k0 = blk * 8;
#pragma unroll
    for (int r = 0; r < 2; ++r) {
      int idx = tid + r * 256;
      int kk = idx >> 6, o = idx & 63;                   // coalesced over o
      SH[o * QSTR + kk] = Wv[(size_t)(k0 + kk) * DD + o];
    }
    __syncthreads();
#pragma unroll
    for (int r = 0; r < 2; ++r) {
      int idx = tid + r * 256;
      int o = idx >> 3, kk = idx & 7;                    // coalesced over kk
      float wv = SH[o * QSTR + kk];
      unsigned short hi = f2bf(wv);
      WvTh[(size_t)o * 512 + k0 + kk] = hi;
      WvTl[(size_t)o * 512 + k0 + kk] = f2bf(wv - bf2f(hi));
    }
  }
}

// ---- Pass 2: hierarchical exclusive scan over 256 chunks, 4-way segmented ----
__global__ __launch_bounds__(576) void k_pass2(float* __restrict__ agg) {
  const int bp = blockIdx.x;
  const int tid = threadIdx.x;
  __shared__ float totals[4][132];

  const bool act = tid < 520;
  int seg = 0, m = 0;
  float* base = agg;
  float vals[64];
  if (act) {
    seg = tid / 130;
    m = tid - seg * 130;
    base = agg + (size_t)bp * NCH * AGG_STRIDE + m;
    float run = 0.f;
#pragma unroll
    for (int u = 0; u < 64; ++u) vals[u] = base[(size_t)(seg * 64 + u) * AGG_STRIDE];
#pragma unroll
    for (int u = 0; u < 64; ++u) run += vals[u];
    totals[seg][m] = run;
  }
  __syncthreads();
  if (act) {
    float r2 = 0.f;
    for (int s = 0; s < seg; ++s) r2 += totals[s][m];
#pragma unroll
    for (int u = 0; u < 64; ++u) {
      float v = vals[u];
      base[(size_t)(seg * 64 + u) * AGG_STRIDE] = r2;
      r2 += v;
    }
  }
}

// ---- Pass 3: trig+scan -> Z(hi/lo bf16, 5-bit swizzle) -> 3-term MFMA GEMM ----
__global__ __launch_bounds__(256, 3) void k_pass3(
    const float* __restrict__ q, const float* __restrict__ Wq,
    const float* __restrict__ Wk, const float* __restrict__ Wo,
    const float* __restrict__ pref,
    const unsigned short* __restrict__ WvTh,
    const unsigned short* __restrict__ WvTl,
    float* __restrict__ out) {
  const int blk = blockIdx.x;
  const int c = blk & (NCH - 1);
  const int b = blk >> 8;

  __shared__ float Qs[CC * QSTR];                          // 8.7 KB
  __shared__ float Wqs[PP * DD], Wks[PP * DD];             // 4 KB
  __shared__ float2 kts[PP * 32];                          // {ck,sk} 2 KB
  __shared__ float2 abt[PP * 32];                          // {al,be} 2 KB
  __shared__ __align__(16) short Zh[CC * 256];             // 16 KB (swizzled)
  __shared__ __align__(16) short Zl[CC * 256];             // 16 KB

  const int tid = threadIdx.x;
  const int w = tid >> 6, l = tid & 63;
  const int lm = l & 15, lg = l >> 4;
  const int oc = w << 4;                                   // wave's 16 o-cols

  // Prefetch h=0 B-fragments (WvT) into registers — independent of all LDS.
  short8 bhf[8], blf[8];
  {
    const unsigned short* ph_ = WvTh + (size_t)(oc + lm) * 512 + lg * 8;
    const unsigned short* pl_ = WvTl + (size_t)(oc + lm) * 512 + lg * 8;
#pragma unroll
    for (int kk = 0; kk < 8; ++kk) {
      bhf[kk] = *(const short8*)(ph_ + kk * 32);
      blf[kk] = *(const short8*)(pl_ + kk * 32);
    }
  }

  const float* qb = q + ((size_t)b * TT + (size_t)c * CC) * DD;
  for (int g = tid; g < CC * DD; g += 256) Qs[(g >> 6) * QSTR + (g & 63)] = qb[g];
  for (int g = tid; g < PP * DD; g += 256) { Wqs[g] = Wq[g]; Wks[g] = Wk[g]; }
  __syncthreads();

  // Phase A: dots + trig + in-segment shfl scan -> packed {ck,sk},{al,be}.
  {
    const int t = tid & 31, p = tid >> 5;
    float dq = 0.f, dk = 0.f;
    const float4* qr  = (const float4*)&Qs[t * QSTR];
    const float4* wqr = (const float4*)&Wqs[p * DD];
    const float4* wkr = (const float4*)&Wks[p * DD];
#pragma unroll
    for (int j = 0; j < 16; ++j) {
      float4 qv = qr[j], w0 = wqr[j], w1 = wkr[j];
      dq = fmaf(qv.x, w0.x, dq); dq = fmaf(qv.y, w0.y, dq);
      dq = fmaf(qv.z, w0.z, dq); dq = fmaf(qv.w, w0.w, dq);
      dk = fmaf(qv.x, w1.x, dk); dk = fmaf(qv.y, w1.y, dk);
      dk = fmaf(qv.z, w1.z, dk); dk = fmaf(qv.w, w1.w, dk);
    }
    float ang = fast_tanh(dq) * KPI4;
    float cq = __cosf(ang), sq = __sinf(ang);
    ang = fast_tanh(dk) * KPI4;
    float ck = __cosf(ang), sk = __sinf(ang);
    kts[p * 32 + t] = make_float2(ck, sk);

    // width-32 inclusive scan over t of (ck, sk), per p-segment
    float rc = ck, rs = sk;
#pragma unroll
    for (int d = 1; d < 32; d <<= 1) {
      float tc = __shfl_up(rc, (unsigned)d, 32);
      float ts = __shfl_up(rs, (unsigned)d, 32);
      if (t >= d) { rc += tc; rs += ts; }
    }
    const float* pr = pref + (size_t)((b * PP + p) * NCH + c) * AGG_STRIDE;
    rc += pr[128]; rs += pr[129];
    float den = fmaf(cq, rc, fmaf(sq, rs, EPSV));
    float ws = Wo[p] * __builtin_amdgcn_rcpf(den);
    abt[p * 32 + t] = make_float2(ws * cq, ws * sq);
  }
  __syncthreads();

  char* zbaseH = (char*)Zh;
  char* zbaseL = (char*)Zl;
  f32x4 acc0 = {0, 0, 0, 0}, acc1 = {0, 0, 0, 0};

#pragma unroll
  for (int h = 0; h < 2; ++h) {
    {  // Phase B(h): thread = (i=l, ph=w); p = h*4+w; k_half = w*64+l.
      const int p = h * 4 + w;
      const float* prC = pref + (size_t)((b * PP + p) * NCH + c) * AGG_STRIDE;
      float Ac = prC[l], As = prC[64 + l];
      const int kb = (w * 64 + l) * 2;     // byte offset of this k in a Z row
#pragma unroll 8
      for (int t = 0; t < CC; ++t) {
        float qv = Qs[t * QSTR + l];
        float2 ks = kts[p * 32 + t];
        float2 ab = abt[p * 32 + t];
        Ac = fmaf(ks.x, qv, Ac);
        As = fmaf(ks.y, qv, As);
        float z = fmaf(ab.x, Ac, ab.y * As);
        unsigned u = __float_as_uint(z);
        unsigned r = u + 0x7fffu + ((u >> 16) & 1u);
        const int ad = (t << 9) + (kb ^ (t << 4));   // 5-bit slot swizzle
        *(short*)(zbaseH + ad) = (short)(r >> 16);
        float lo = z - __uint_as_float(r & 0xffff0000u);
        *(short*)(zbaseL + ad) = (short)(__float_as_uint(lo) >> 16);
      }
    }
    __syncthreads();
    // Phase C(h): pure ds_read + MFMA (B-frags already in registers).
#pragma unroll
    for (int kk = 0; kk < 8; ++kk) {
      const int base = kk * 64 + lg * 16;
      const int rb0 = (lm << 9) + (base ^ (lm << 4));
      const int rb1 = ((16 + lm) << 9) + (base ^ ((16 + lm) << 4));
      short8 ah0 = *(const short8*)(zbaseH + rb0);
      short8 al0 = *(const short8*)(zbaseL + rb0);
      short8 ah1 = *(const short8*)(zbaseH + rb1);
      short8 al1 = *(const short8*)(zbaseL + rb1);
      acc0 = __builtin_amdgcn_mfma_f32_16x16x32_bf16(ah0, bhf[kk], acc0, 0, 0, 0);
      acc1 = __builtin_amdgcn_mfma_f32_16x16x32_bf16(ah1, bhf[kk], acc1, 0, 0, 0);
      acc0 = __builtin_amdgcn_mfma_f32_16x16x32_bf16(al0, bhf[kk], acc0, 0, 0, 0);
      acc1 = __builtin_amdgcn_mfma_f32_16x16x32_bf16(al1, bhf[kk], acc1, 0, 0, 0);
      acc0 = __builtin_amdgcn_mfma_f32_16x16x32_bf16(ah0, blf[kk], acc0, 0, 0, 0);
      acc1 = __builtin_amdgcn_mfma_f32_16x16x32_bf16(ah1, blf[kk], acc1, 0, 0, 0);
    }
    if (h == 0) {  // prefetch h=1 B-fragments; latency hides under B(1)
      const unsigned short* ph_ = WvTh + (size_t)(oc + lm) * 512 + 256 + lg * 8;
      const unsigned short* pl_ = WvTl + (size_t)(oc + lm) * 512 + 256 + lg * 8;
#pragma unroll
      for (int kk = 0; kk < 8; ++kk) {
        bhf[kk] = *(const short8*)(ph_ + kk * 32);
        blf[kk] = *(const short8*)(pl_ + kk * 32);
      }
    }
    __syncthreads();
  }

  // Epilogue: C/D layout col=lane&15 (o), row=(lane>>4)*4+reg (t)  [m89]
  {
    float* ob = out + ((size_t)b * TT + (size_t)c * CC + lg * 4) * DD + oc + lm;
#pragma unroll
    for (int r = 0; r < 4; ++r) {
      ob[r * DD] = acc0[r];
      ob[(16 + r) * DD] = acc1[r];
    }
  }
}

extern "C" void kernel_launch(void* const* d_in, const int* in_sizes, int n_in,
                              void* d_out, int out_size, void* d_ws, size_t ws_size,
                              hipStream_t stream) {
  const float* q  = (const float*)d_in[0];
  const float* Wq = (const float*)d_in[1];
  const float* Wk = (const float*)d_in[2];
  const float* Wv = (const float*)d_in[3];
  const float* Wo = (const float*)d_in[4];
  float* out = (float*)d_out;
  float* agg = (float*)d_ws;  // BB*PP*NCH*130 floats = 4,259,840 B
  unsigned short* WvTh = (unsigned short*)(agg + (size_t)BB * PP * NCH * AGG_STRIDE);
  unsigned short* WvTl = WvTh + (size_t)512 * 64;   // +64 KB each

  k_pass1<<<BB * NCH, 256, 0, stream>>>(q, Wk, Wv, agg, WvTh, WvTl);
  k_pass2<<<BB * PP, 576, 0, stream>>>(agg);
  k_pass3<<<BB * NCH, 256, 0, stream>>>(q, Wq, Wk, Wo, agg, WvTh, WvTl, out);
}